// Round 6
// baseline (269.348 us; speedup 1.0000x reference)
//
#include <hip/hip_runtime.h>

typedef __bf16 bf16;
typedef __bf16 bf16x8 __attribute__((ext_vector_type(8)));
typedef float f32x4 __attribute__((ext_vector_type(4)));
typedef unsigned long long u64;

#define MFMA16(a, b, c) __builtin_amdgcn_mfma_f32_16x16x32_bf16(a, b, c, 0, 0, 0)

// Async global->LDS, 16 B per lane. LDS dest is wave-uniform base; lane i's
// data lands at base + i*16 (m97 pattern).
__device__ __forceinline__ void gl_lds16(const void* g, void* l) {
  __builtin_amdgcn_global_load_lds(
      (const __attribute__((address_space(1))) unsigned int*)g,
      (__attribute__((address_space(3))) unsigned int*)l, 16, 0, 0);
}

// ---------------------------------------------------------------------------
// f32 -> bf16 elementwise downcast (context pre-conversion). 8 elems/thread.
// ---------------------------------------------------------------------------
__global__ __launch_bounds__(256)
void cvt_f32_bf16_k(const float* __restrict__ src, bf16* __restrict__ dst) {
  const size_t i = ((size_t)blockIdx.x * 256 + threadIdx.x) * 8;
  f32x4 a0 = *(const f32x4*)(src + i);
  f32x4 a1 = *(const f32x4*)(src + i + 4);
  bf16x8 t;
#pragma unroll
  for (int j = 0; j < 4; ++j) { t[j] = (bf16)a0[j]; t[4 + j] = (bf16)a1[j]; }
  *(bf16x8*)(dst + i) = t;
}

// ---------------------------------------------------------------------------
// Weight transpose+downcast. ct (= blockIdx.x + ct_off):
//   0..15  -> Wq  cols -> BqkvT rows 0..1023
//   16..47 -> Wkv cols -> BqkvT rows 1024..3071
//   48..63 -> Wp  cols -> WpT
// ---------------------------------------------------------------------------
__global__ __launch_bounds__(256)
void transpose_weights_k(const float* __restrict__ Wq,
                         const float* __restrict__ Wkv,
                         const float* __restrict__ Wp,
                         bf16* __restrict__ BqkvT, bf16* __restrict__ WpT,
                         int ct_off) {
  const int ct = blockIdx.x + ct_off, rt = blockIdx.y;
  const float* src;
  bf16* dst;
  int C, c0, drow0;
  if (ct < 16) {
    src = Wq; C = 1024; c0 = ct * 64; dst = BqkvT; drow0 = c0;
  } else if (ct < 48) {
    src = Wkv; C = 2048; c0 = (ct - 16) * 64; dst = BqkvT; drow0 = 1024 + c0;
  } else {
    src = Wp; C = 1024; c0 = (ct - 48) * 64; dst = WpT; drow0 = c0;
  }
  __shared__ bf16 T[64][72];
  const int tid = threadIdx.x;
  const int r0 = rt * 64;
#pragma unroll
  for (int i = 0; i < 2; ++i) {
    int c = i * 256 + tid;
    int row = c >> 3, col = (c & 7) * 8;
    const float* sp = &src[(size_t)(r0 + row) * C + c0 + col];
    f32x4 a0 = *(const f32x4*)sp;
    f32x4 a1 = *(const f32x4*)(sp + 4);
    bf16x8 t;
#pragma unroll
    for (int j = 0; j < 4; ++j) { t[j] = (bf16)a0[j]; t[4 + j] = (bf16)a1[j]; }
    *(bf16x8*)&T[row][col] = t;
  }
  __syncthreads();
#pragma unroll
  for (int i = 0; i < 2; ++i) {
    int c = i * 256 + tid;
    int orow = c >> 3, ocol = (c & 7) * 8;
    bf16x8 v;
#pragma unroll
    for (int j = 0; j < 8; ++j) v[j] = T[ocol + j][orow];
    *(bf16x8*)&dst[(size_t)(drow0 + orow) * 1024 + r0 + ocol] = v;
  }
}

// ---------------------------------------------------------------------------
// Pack int32 mask [4][1024][1024] -> u64 bit-words [4096][16].
// ---------------------------------------------------------------------------
__global__ __launch_bounds__(256)
void maskpack_k(const int* __restrict__ mask, u64* __restrict__ out) {
  const int idx = blockIdx.x * 256 + threadIdx.x;  // 0..65535
  const int4* p = (const int4*)(mask + (size_t)idx * 64);
  u64 v = 0;
#pragma unroll
  for (int i = 0; i < 16; ++i) {
    int4 m = p[i];
    v |= (u64)(m.x != 0) << (4 * i);
    v |= (u64)(m.y != 0) << (4 * i + 1);
    v |= (u64)(m.z != 0) << (4 * i + 2);
    v |= (u64)(m.w != 0) << (4 * i + 3);
  }
  out[idx] = v;
}

// ---------------------------------------------------------------------------
// Fused QKV GEMM, m97 structure: 128x128 tile, BK=64, unpadded LDS staged by
// global_load_lds (KV side A and all B); Q side A is f32 (cvt in VGPRs).
// grid = (24, 32) = 768 blocks (3/CU). Epilogue scatters Q*SCALE2 -> qw,
// K -> kw, V -> vtw (pre-transposed).
// ---------------------------------------------------------------------------
__global__ __launch_bounds__(256)
void gemm_qkv(const float* __restrict__ xf, const bf16* __restrict__ cb,
              const bf16* __restrict__ Bt, const float* __restrict__ bq,
              const float* __restrict__ bkv, bf16* __restrict__ oq,
              bf16* __restrict__ ok, bf16* __restrict__ ovt) {
  __shared__ bf16 As[128][64];
  __shared__ bf16 Bs[128][64];
  const int tid = threadIdx.x;
  const int lane = tid & 63;
  const int w = tid >> 6;
  const int wm = (w >> 1) * 64, wn = (w & 1) * 64;
  const int l15 = lane & 15, l4 = lane >> 4;
  const int lrow = lane >> 3, lcol = (lane & 7) * 8;
  const int n0g = blockIdx.x * 128;
  const int m0 = blockIdx.y * 128;
  const bool qside = (n0g < 1024);

  // Q-side f32 staging coords: 32 f32 per thread.
  const int ar = tid >> 1, ac0 = (tid & 1) * 32;

  f32x4 acc[4][4] = {};

  for (int kk = 0; kk < 1024; kk += 64) {
    // B tile: 4 global_load_lds issues per wave.
#pragma unroll
    for (int it = 0; it < 4; ++it) {
      const int r = w * 32 + it * 8;
      gl_lds16(&Bt[(size_t)(n0g + r + lrow) * 1024 + kk + lcol], &Bs[r][0]);
    }
    if (qside) {
      const float* ap = &xf[(size_t)(m0 + ar) * 1024 + kk + ac0];
#pragma unroll
      for (int h = 0; h < 4; ++h) {
        f32x4 a0 = *(const f32x4*)(ap + h * 8);
        f32x4 a1 = *(const f32x4*)(ap + h * 8 + 4);
        bf16x8 t;
#pragma unroll
        for (int j = 0; j < 4; ++j) { t[j] = (bf16)a0[j]; t[4 + j] = (bf16)a1[j]; }
        *(bf16x8*)&As[ar][ac0 + h * 8] = t;
      }
    } else {
#pragma unroll
      for (int it = 0; it < 4; ++it) {
        const int r = w * 32 + it * 8;
        gl_lds16(&cb[(size_t)(m0 + r + lrow) * 1024 + kk + lcol], &As[r][0]);
      }
    }
    __syncthreads();
#pragma unroll
    for (int ks = 0; ks < 2; ++ks) {
      bf16x8 af[4], bfr[4];
#pragma unroll
      for (int i = 0; i < 4; ++i)
        af[i] = *(const bf16x8*)&As[wm + i * 16 + l15][ks * 32 + l4 * 8];
#pragma unroll
      for (int j = 0; j < 4; ++j)
        bfr[j] = *(const bf16x8*)&Bs[wn + j * 16 + l15][ks * 32 + l4 * 8];
#pragma unroll
      for (int i = 0; i < 4; ++i)
#pragma unroll
        for (int j = 0; j < 4; ++j)
          acc[i][j] = MFMA16(af[i], bfr[j], acc[i][j]);
    }
    __syncthreads();
  }

  const float SCALE2 = 0.18033688011112042f;  // 1/sqrt(64) * log2(e)
#pragma unroll
  for (int j = 0; j < 4; ++j) {
    const int col = n0g + wn + j * 16 + l15;
    const float bc = (col < 1024) ? bq[col] : bkv[col - 1024];
#pragma unroll
    for (int i = 0; i < 4; ++i) {
#pragma unroll
      for (int r = 0; r < 4; ++r) {
        const int row = m0 + wm + i * 16 + l4 * 4 + r;
        const float v = acc[i][j][r] + bc;
        const int b = row >> 10, n = row & 1023;
        if (col < 1024) {
          const int h = col >> 6, d = col & 63;
          oq[(((size_t)(b * 16 + h)) * 1024 + n) * 64 + d] = (bf16)(v * SCALE2);
        } else {
          const int ckv = col - 1024;
          const int s = ckv >> 10, c2 = ckv & 1023;
          const int h = c2 >> 6, d = c2 & 63;
          if (s == 0)
            ok[(((size_t)(b * 16 + h)) * 1024 + n) * 64 + d] = (bf16)v;
          else
            ovt[(((size_t)(b * 16 + h)) * 64 + d) * 1024 + n] = (bf16)v;
        }
      }
    }
  }
}

// ---------------------------------------------------------------------------
// Output projection GEMM: 64x128 tile, BK=64, all-bf16, global_load_lds
// staging. grid = (8, 64) = 512 blocks. Writes f32.
// ---------------------------------------------------------------------------
__global__ __launch_bounds__(256)
void gemm_op(const bf16* __restrict__ A, const bf16* __restrict__ Bt,
             const float* __restrict__ bias, float* __restrict__ out) {
  __shared__ bf16 As[64][64];
  __shared__ bf16 Bs[128][64];
  const int tid = threadIdx.x;
  const int lane = tid & 63;
  const int w = tid >> 6;
  const int wm = (w >> 1) * 32, wn = (w & 1) * 64;
  const int l15 = lane & 15, l4 = lane >> 4;
  const int lrow = lane >> 3, lcol = (lane & 7) * 8;
  const int n0 = blockIdx.x * 128;
  const int m0 = blockIdx.y * 64;

  f32x4 acc[2][4] = {};

  for (int kk = 0; kk < 1024; kk += 64) {
#pragma unroll
    for (int it = 0; it < 4; ++it) {
      const int r = w * 32 + it * 8;
      gl_lds16(&Bt[(size_t)(n0 + r + lrow) * 1024 + kk + lcol], &Bs[r][0]);
    }
#pragma unroll
    for (int it = 0; it < 2; ++it) {
      const int r = w * 16 + it * 8;
      gl_lds16(&A[(size_t)(m0 + r + lrow) * 1024 + kk + lcol], &As[r][0]);
    }
    __syncthreads();
#pragma unroll
    for (int ks = 0; ks < 2; ++ks) {
      bf16x8 af[2], bfr[4];
#pragma unroll
      for (int i = 0; i < 2; ++i)
        af[i] = *(const bf16x8*)&As[wm + i * 16 + l15][ks * 32 + l4 * 8];
#pragma unroll
      for (int j = 0; j < 4; ++j)
        bfr[j] = *(const bf16x8*)&Bs[wn + j * 16 + l15][ks * 32 + l4 * 8];
#pragma unroll
      for (int i = 0; i < 2; ++i)
#pragma unroll
        for (int j = 0; j < 4; ++j)
          acc[i][j] = MFMA16(af[i], bfr[j], acc[i][j]);
    }
    __syncthreads();
  }

#pragma unroll
  for (int j = 0; j < 4; ++j) {
    const int col = n0 + wn + j * 16 + l15;
    const float bc = bias[col];
#pragma unroll
    for (int i = 0; i < 2; ++i) {
#pragma unroll
      for (int r = 0; r < 4; ++r) {
        const int row = m0 + wm + i * 16 + l4 * 4 + r;
        out[(size_t)row * 1024 + col] = acc[i][j][r] + bc;
      }
    }
  }
}

// ---------------------------------------------------------------------------
// Flash-style masked attention, fixed-max softmax, bit-packed mask.
// (unchanged from round 5)
// ---------------------------------------------------------------------------
__global__ __launch_bounds__(256)
void attn_kernel(const bf16* __restrict__ q, const bf16* __restrict__ k,
                 const bf16* __restrict__ vT, const u64* __restrict__ maskbits,
                 bf16* __restrict__ ao) {
  const int ntile = blockIdx.x;
  const int bh = blockIdx.y;
  const int b = bh >> 4, h = bh & 15;
  const int tid = threadIdx.x;
  const int lane = tid & 63;
  const int w = tid >> 6;
  const int l15 = lane & 15, l4 = lane >> 4;

  __shared__ bf16 Ks[64][72];
  __shared__ bf16 Vts[64][72];
  __shared__ bf16 Pw[4][16][72];

  const size_t base = (size_t)bh * 65536;
  const int nrow0 = ntile * 64 + w * 16;

  bf16x8 qf[2];
#pragma unroll
  for (int ks = 0; ks < 2; ++ks)
    qf[ks] =
        *(const bf16x8*)&q[base + (size_t)(nrow0 + l15) * 64 + ks * 32 + l4 * 8];

  f32x4 o[4] = {};
  float lsum[4] = {0.0f, 0.0f, 0.0f, 0.0f};

  const u64* mb = maskbits + (size_t)(b * 1024 + nrow0) * 16;

  for (int mt = 0; mt < 16; ++mt) {
#pragma unroll
    for (int i = 0; i < 2; ++i) {
      int c = i * 256 + tid;
      int row = c >> 3, col = (c & 7) * 8;
      *(bf16x8*)&Ks[row][col] =
          *(const bf16x8*)&k[base + (size_t)(mt * 64 + row) * 64 + col];
      *(bf16x8*)&Vts[row][col] =
          *(const bf16x8*)&vT[base + (size_t)row * 1024 + mt * 64 + col];
    }
    __syncthreads();

    f32x4 s[4];
#pragma unroll
    for (int sub = 0; sub < 4; ++sub) s[sub] = f32x4{-12.f, -12.f, -12.f, -12.f};
#pragma unroll
    for (int ks = 0; ks < 2; ++ks) {
#pragma unroll
      for (int sub = 0; sub < 4; ++sub) {
        bf16x8 bfr = *(const bf16x8*)&Ks[sub * 16 + l15][ks * 32 + l4 * 8];
        s[sub] = MFMA16(qf[ks], bfr, s[sub]);
      }
    }

    u64 wbits[4];
#pragma unroll
    for (int r = 0; r < 4; ++r) wbits[r] = mb[(size_t)(l4 * 4 + r) * 16 + mt];

#pragma unroll
    for (int sub = 0; sub < 4; ++sub) {
#pragma unroll
      for (int r = 0; r < 4; ++r) {
        float p = exp2f(s[sub][r]);
        p = ((wbits[r] >> (sub * 16 + l15)) & 1) ? p : 0.0f;
        lsum[r] += p;
        Pw[w][l4 * 4 + r][sub * 16 + l15] = (bf16)p;
      }
    }

#pragma unroll
    for (int ks = 0; ks < 2; ++ks) {
      bf16x8 af = *(const bf16x8*)&Pw[w][l15][ks * 32 + l4 * 8];
#pragma unroll
      for (int sub = 0; sub < 4; ++sub) {
        bf16x8 bfr = *(const bf16x8*)&Vts[sub * 16 + l15][ks * 32 + l4 * 8];
        o[sub] = MFMA16(af, bfr, o[sub]);
      }
    }
    __syncthreads();
  }

  float inv[4];
#pragma unroll
  for (int r = 0; r < 4; ++r) {
    float t = lsum[r];
#pragma unroll
    for (int d = 1; d < 16; d <<= 1) t += __shfl_xor(t, d);
    inv[r] = 1.0f / t;
  }

#pragma unroll
  for (int sub = 0; sub < 4; ++sub) {
#pragma unroll
    for (int r = 0; r < 4; ++r) {
      const int n = nrow0 + l4 * 4 + r;
      const size_t idx =
          ((size_t)(b * 1024 + n)) * 1024 + h * 64 + sub * 16 + l15;
      ao[idx] = (bf16)(o[sub][r] * inv[r]);
    }
  }
}

// ---------------------------------------------------------------------------
extern "C" void kernel_launch(void* const* d_in, const int* in_sizes, int n_in,
                              void* d_out, int out_size, void* d_ws,
                              size_t ws_size, hipStream_t stream) {
  const float* x = (const float*)d_in[0];        // [4,1024,1024]
  const float* context = (const float*)d_in[1];  // [4,1024,1024]
  const int* mask = (const int*)d_in[2];         // [4,1024,32,32]
  const float* Wq = (const float*)d_in[3];
  const float* bq = (const float*)d_in[4];
  const float* Wkv = (const float*)d_in[5];
  const float* bkv = (const float*)d_in[6];
  const float* Wp = (const float*)d_in[7];
  const float* bp = (const float*)d_in[8];
  float* out = (float*)d_out;                    // [4,1024,1024] f32

  // Workspace: 38 MB with time-sliced region reuse.
  //  @0  (8 MB): cb  (conv -> QKV GEMM)        ... then aow (attn -> O-proj)
  //  @8  (6 MB): BqkvT (transpose -> QKV GEMM) ... then maskbits @8 (512 KB)
  //                                                 + WpT @9 (2 MB)
  //  @14 (8 MB): qw    @22 (8 MB): kw    @30 (8 MB): vtw
  char* ws = (char*)d_ws;
  bf16* cb = (bf16*)(ws);
  bf16* aow = (bf16*)(ws);
  bf16* BqkvT = (bf16*)(ws + (8ull << 20));
  u64* maskbits = (u64*)(ws + (8ull << 20));
  bf16* WpT = (bf16*)(ws + (9ull << 20));
  bf16* qw = (bf16*)(ws + (14ull << 20));
  bf16* kw = (bf16*)(ws + (22ull << 20));
  bf16* vtw = (bf16*)(ws + (30ull << 20));

  const dim3 blk(256);

  // context f32 -> bf16.
  cvt_f32_bf16_k<<<dim3(2048), blk, 0, stream>>>(context, cb);

  // Wq + Wkv transposes -> BqkvT.
  transpose_weights_k<<<dim3(48, 16), blk, 0, stream>>>(Wq, Wkv, Wp, BqkvT,
                                                        WpT, 0);

  // Fused QKV projection (768 blocks, 3/CU).
  gemm_qkv<<<dim3(24, 32), blk, 0, stream>>>(x, cb, BqkvT, bq, bkv, qw, kw,
                                             vtw);

  // Mask pack + Wp transpose (both into the dead BqkvT region).
  maskpack_k<<<dim3(256), blk, 0, stream>>>(mask, maskbits);
  transpose_weights_k<<<dim3(16, 16), blk, 0, stream>>>(Wq, Wkv, Wp, BqkvT,
                                                        WpT, 48);

  // Attention (aow overwrites the dead cb region).
  attn_kernel<<<dim3(16, 64), blk, 0, stream>>>(qw, kw, vtw, maskbits, aow);

  // Output projection (512 blocks).
  gemm_op<<<dim3(8, 64), blk, 0, stream>>>(aow, WpT, bp, out);
}

// Round 7
// 241.244 us; speedup vs baseline: 1.1165x; 1.1165x over previous
//
#include <hip/hip_runtime.h>

typedef __bf16 bf16;
typedef __bf16 bf16x8 __attribute__((ext_vector_type(8)));
typedef float f32x4 __attribute__((ext_vector_type(4)));
typedef unsigned long long u64;

#define MFMA16(a, b, c) __builtin_amdgcn_mfma_f32_16x16x32_bf16(a, b, c, 0, 0, 0)

// Async global->LDS, 16 B/lane; LDS dest = wave-uniform base + lane*16.
__device__ __forceinline__ void gl_lds16(const void* g, void* l) {
  __builtin_amdgcn_global_load_lds(
      (const __attribute__((address_space(1))) unsigned int*)g,
      (__attribute__((address_space(3))) unsigned int*)l, 16, 0, 0);
}

// ---------------------------------------------------------------------------
// Fused prep: blocks 0..1023 transpose+downcast weights (ct = bx>>4: 0..15 Wq,
// 16..47 Wkv -> BqkvT; 48..63 Wp -> WpT); blocks 1024..1279 pack the mask.
// ---------------------------------------------------------------------------
__global__ __launch_bounds__(256)
void prep_k(const float* __restrict__ Wq, const float* __restrict__ Wkv,
            const float* __restrict__ Wp, const int* __restrict__ mask,
            bf16* __restrict__ BqkvT, bf16* __restrict__ WpT,
            u64* __restrict__ maskbits) {
  const int bx = blockIdx.x;
  const int tid = threadIdx.x;
  if (bx >= 1024) {  // ---- mask pack: [4][1024][1024] i32 -> [4096][16] u64
    const int idx = (bx - 1024) * 256 + tid;
    const int4* p = (const int4*)(mask + (size_t)idx * 64);
    u64 v = 0;
#pragma unroll
    for (int i = 0; i < 16; ++i) {
      int4 m = p[i];
      v |= (u64)(m.x != 0) << (4 * i);
      v |= (u64)(m.y != 0) << (4 * i + 1);
      v |= (u64)(m.z != 0) << (4 * i + 2);
      v |= (u64)(m.w != 0) << (4 * i + 3);
    }
    maskbits[idx] = v;
    return;
  }
  // ---- weight transpose tile
  const int ct = bx >> 4, rt = bx & 15;
  const float* src;
  bf16* dst;
  int C, c0, drow0;
  if (ct < 16) {
    src = Wq; C = 1024; c0 = ct * 64; dst = BqkvT; drow0 = c0;
  } else if (ct < 48) {
    src = Wkv; C = 2048; c0 = (ct - 16) * 64; dst = BqkvT; drow0 = 1024 + c0;
  } else {
    src = Wp; C = 1024; c0 = (ct - 48) * 64; dst = WpT; drow0 = c0;
  }
  __shared__ bf16 T[64][72];
  const int r0 = rt * 64;
#pragma unroll
  for (int i = 0; i < 2; ++i) {
    int c = i * 256 + tid;
    int row = c >> 3, col = (c & 7) * 8;
    const float* sp = &src[(size_t)(r0 + row) * C + c0 + col];
    f32x4 a0 = *(const f32x4*)sp;
    f32x4 a1 = *(const f32x4*)(sp + 4);
    bf16x8 t;
#pragma unroll
    for (int j = 0; j < 4; ++j) { t[j] = (bf16)a0[j]; t[4 + j] = (bf16)a1[j]; }
    *(bf16x8*)&T[row][col] = t;
  }
  __syncthreads();
#pragma unroll
  for (int i = 0; i < 2; ++i) {
    int c = i * 256 + tid;
    int orow = c >> 3, ocol = (c & 7) * 8;
    bf16x8 v;
#pragma unroll
    for (int j = 0; j < 8; ++j) v[j] = T[ocol + j][orow];
    *(bf16x8*)&dst[(size_t)(drow0 + orow) * 1024 + r0 + ocol] = v;
  }
}

// ---------------------------------------------------------------------------
// Swizzled GEMM, 64(M)x128(N) tile, BK=64, 256 threads (4 waves, 2x2 wave
// grid: each wave 32x64 = 2x4 MFMA 16x16x32). LDS unpadded [rows][64] with
// XOR column-block swizzle: logical 16B block cb of row r lives at physical
// block cb^(r&7). Staged by global_load_lds (source-permuted per lane) ->
// conflict-free ds_read_b128 fragment reads (8 dwords/bank minimum).
//   EPI 1 (QKV): A = f32 x/context (VGPR cvt staging, swizzled ds_write);
//                epilogue scatters Q*SCALE2 -> oq, K -> ok, V^T -> ovt.
//   EPI 0 (OP):  A = bf16 (async), writes f32 out.
// ---------------------------------------------------------------------------
template <int EPI>
__global__ __launch_bounds__(256)
void gemm_sw(const float* __restrict__ Af0, const float* __restrict__ Af1,
             const bf16* __restrict__ Ab, const bf16* __restrict__ Bt,
             const float* __restrict__ bias0, const float* __restrict__ bias1,
             bf16* __restrict__ oq, bf16* __restrict__ ok,
             bf16* __restrict__ ovt, float* __restrict__ outf) {
  __shared__ bf16 As[64][64];
  __shared__ bf16 Bs[128][64];
  const int tid = threadIdx.x;
  const int lane = tid & 63;
  const int w = tid >> 6;
  const int wm = (w >> 1) * 32, wn = (w & 1) * 64;
  const int l15 = lane & 15, l4 = lane >> 4;
  const int lrow = lane >> 3;
  const int scol = ((lane & 7) ^ (lrow & 7)) * 8;  // swizzled source column
  const int n0 = blockIdx.x * 128;
  const int m0 = blockIdx.y * 64;

  const float* Asrc = (EPI == 1) ? ((n0 < 1024) ? Af0 : Af1) : nullptr;

  // f32 A staging coords (EPI 1): thread covers row ar, logical blocks
  // acb, acb+1 (16 f32 each K-iter).
  const int ar = tid >> 2;
  const int acb = (tid & 3) * 2;

  f32x4 acc[2][4] = {};

  for (int kk = 0; kk < 1024; kk += 64) {
    // B tile (128x64): 4 async 1KB stages per wave.
#pragma unroll
    for (int it = 0; it < 4; ++it) {
      const int r = w * 32 + it * 8;
      gl_lds16(&Bt[(size_t)(n0 + r + lrow) * 1024 + kk + scol], &Bs[r][0]);
    }
    if (EPI == 0) {
      // A tile (64x64): 2 async stages per wave.
#pragma unroll
      for (int it = 0; it < 2; ++it) {
        const int r = w * 16 + it * 8;
        gl_lds16(&Ab[(size_t)(m0 + r + lrow) * 1024 + kk + scol], &As[r][0]);
      }
    } else {
      // A tile from f32: cvt in VGPRs, swizzled ds_write_b128.
#pragma unroll
      for (int j = 0; j < 2; ++j) {
        const int cbL = acb + j;
        const float* ap = &Asrc[(size_t)(m0 + ar) * 1024 + kk + cbL * 8];
        f32x4 a0 = *(const f32x4*)ap;
        f32x4 a1 = *(const f32x4*)(ap + 4);
        bf16x8 t;
#pragma unroll
        for (int u = 0; u < 4; ++u) { t[u] = (bf16)a0[u]; t[4 + u] = (bf16)a1[u]; }
        *(bf16x8*)&As[ar][(cbL ^ (ar & 7)) * 8] = t;
      }
    }
    __syncthreads();
#pragma unroll
    for (int ks = 0; ks < 2; ++ks) {
      const int sw = ((ks * 4 + l4) ^ (l15 & 7)) * 8;  // physical col offset
      bf16x8 af[2], bfr[4];
#pragma unroll
      for (int i = 0; i < 2; ++i)
        af[i] = *(const bf16x8*)&As[wm + i * 16 + l15][sw];
#pragma unroll
      for (int j = 0; j < 4; ++j)
        bfr[j] = *(const bf16x8*)&Bs[wn + j * 16 + l15][sw];
#pragma unroll
      for (int i = 0; i < 2; ++i)
#pragma unroll
        for (int j = 0; j < 4; ++j)
          acc[i][j] = MFMA16(af[i], bfr[j], acc[i][j]);
    }
    __syncthreads();
  }

  const float SCALE2 = 0.18033688011112042f;  // 1/sqrt(64) * log2(e)
#pragma unroll
  for (int j = 0; j < 4; ++j) {
    const int col = n0 + wn + j * 16 + l15;
    float bc;
    if (EPI == 1) bc = (col < 1024) ? bias0[col] : bias1[col - 1024];
    else bc = bias0[col];
#pragma unroll
    for (int i = 0; i < 2; ++i) {
#pragma unroll
      for (int r = 0; r < 4; ++r) {
        const int row = m0 + wm + i * 16 + l4 * 4 + r;
        const float v = acc[i][j][r] + bc;
        if (EPI == 0) {
          outf[(size_t)row * 1024 + col] = v;
        } else {
          const int b = row >> 10, n = row & 1023;
          if (col < 1024) {
            const int h = col >> 6, d = col & 63;
            oq[(((size_t)(b * 16 + h)) * 1024 + n) * 64 + d] =
                (bf16)(v * SCALE2);
          } else {
            const int ckv = col - 1024;
            const int s = ckv >> 10, c2 = ckv & 1023;
            const int h = c2 >> 6, d = c2 & 63;
            if (s == 0)
              ok[(((size_t)(b * 16 + h)) * 1024 + n) * 64 + d] = (bf16)v;
            else
              ovt[(((size_t)(b * 16 + h)) * 64 + d) * 1024 + n] = (bf16)v;
          }
        }
      }
    }
  }
}

// ---------------------------------------------------------------------------
// Flash-style masked attention, fixed-max softmax, bit-packed mask
// (unchanged from round 5).
// ---------------------------------------------------------------------------
__global__ __launch_bounds__(256)
void attn_kernel(const bf16* __restrict__ q, const bf16* __restrict__ k,
                 const bf16* __restrict__ vT, const u64* __restrict__ maskbits,
                 bf16* __restrict__ ao) {
  const int ntile = blockIdx.x;
  const int bh = blockIdx.y;
  const int b = bh >> 4, h = bh & 15;
  const int tid = threadIdx.x;
  const int lane = tid & 63;
  const int w = tid >> 6;
  const int l15 = lane & 15, l4 = lane >> 4;

  __shared__ bf16 Ks[64][72];
  __shared__ bf16 Vts[64][72];
  __shared__ bf16 Pw[4][16][72];

  const size_t base = (size_t)bh * 65536;
  const int nrow0 = ntile * 64 + w * 16;

  bf16x8 qf[2];
#pragma unroll
  for (int ks = 0; ks < 2; ++ks)
    qf[ks] =
        *(const bf16x8*)&q[base + (size_t)(nrow0 + l15) * 64 + ks * 32 + l4 * 8];

  f32x4 o[4] = {};
  float lsum[4] = {0.0f, 0.0f, 0.0f, 0.0f};

  const u64* mb = maskbits + (size_t)(b * 1024 + nrow0) * 16;

  for (int mt = 0; mt < 16; ++mt) {
#pragma unroll
    for (int i = 0; i < 2; ++i) {
      int c = i * 256 + tid;
      int row = c >> 3, col = (c & 7) * 8;
      *(bf16x8*)&Ks[row][col] =
          *(const bf16x8*)&k[base + (size_t)(mt * 64 + row) * 64 + col];
      *(bf16x8*)&Vts[row][col] =
          *(const bf16x8*)&vT[base + (size_t)row * 1024 + mt * 64 + col];
    }
    __syncthreads();

    f32x4 s[4];
#pragma unroll
    for (int sub = 0; sub < 4; ++sub) s[sub] = f32x4{-12.f, -12.f, -12.f, -12.f};
#pragma unroll
    for (int ks = 0; ks < 2; ++ks) {
#pragma unroll
      for (int sub = 0; sub < 4; ++sub) {
        bf16x8 bfr = *(const bf16x8*)&Ks[sub * 16 + l15][ks * 32 + l4 * 8];
        s[sub] = MFMA16(qf[ks], bfr, s[sub]);
      }
    }

    u64 wbits[4];
#pragma unroll
    for (int r = 0; r < 4; ++r) wbits[r] = mb[(size_t)(l4 * 4 + r) * 16 + mt];

#pragma unroll
    for (int sub = 0; sub < 4; ++sub) {
#pragma unroll
      for (int r = 0; r < 4; ++r) {
        float p = exp2f(s[sub][r]);
        p = ((wbits[r] >> (sub * 16 + l15)) & 1) ? p : 0.0f;
        lsum[r] += p;
        Pw[w][l4 * 4 + r][sub * 16 + l15] = (bf16)p;
      }
    }

#pragma unroll
    for (int ks = 0; ks < 2; ++ks) {
      bf16x8 af = *(const bf16x8*)&Pw[w][l15][ks * 32 + l4 * 8];
#pragma unroll
      for (int sub = 0; sub < 4; ++sub) {
        bf16x8 bfr = *(const bf16x8*)&Vts[sub * 16 + l15][ks * 32 + l4 * 8];
        o[sub] = MFMA16(af, bfr, o[sub]);
      }
    }
    __syncthreads();
  }

  float inv[4];
#pragma unroll
  for (int r = 0; r < 4; ++r) {
    float t = lsum[r];
#pragma unroll
    for (int d = 1; d < 16; d <<= 1) t += __shfl_xor(t, d);
    inv[r] = 1.0f / t;
  }

#pragma unroll
  for (int sub = 0; sub < 4; ++sub) {
#pragma unroll
    for (int r = 0; r < 4; ++r) {
      const int n = nrow0 + l4 * 4 + r;
      const size_t idx =
          ((size_t)(b * 1024 + n)) * 1024 + h * 64 + sub * 16 + l15;
      ao[idx] = (bf16)(o[sub][r] * inv[r]);
    }
  }
}

// ---------------------------------------------------------------------------
extern "C" void kernel_launch(void* const* d_in, const int* in_sizes, int n_in,
                              void* d_out, int out_size, void* d_ws,
                              size_t ws_size, hipStream_t stream) {
  const float* x = (const float*)d_in[0];        // [4,1024,1024]
  const float* context = (const float*)d_in[1];  // [4,1024,1024]
  const int* mask = (const int*)d_in[2];         // [4,1024,32,32]
  const float* Wq = (const float*)d_in[3];
  const float* bq = (const float*)d_in[4];
  const float* Wkv = (const float*)d_in[5];
  const float* bkv = (const float*)d_in[6];
  const float* Wp = (const float*)d_in[7];
  const float* bp = (const float*)d_in[8];
  float* out = (float*)d_out;                    // [4,1024,1024] f32

  // Workspace (35 MB):
  //  @0  (6 MB): BqkvT  -> dead after QKV; aow (8 MB @0) overwrites it
  //  @8  (8 MB): qw   @16 (8 MB): kw   @24 (8 MB): vtw
  //  @32 (0.5 MB): maskbits   @33 (2 MB): WpT
  char* ws = (char*)d_ws;
  bf16* BqkvT = (bf16*)(ws);
  bf16* aow = (bf16*)(ws);
  bf16* qw = (bf16*)(ws + (8ull << 20));
  bf16* kw = (bf16*)(ws + (16ull << 20));
  bf16* vtw = (bf16*)(ws + (24ull << 20));
  u64* maskbits = (u64*)(ws + (32ull << 20));
  bf16* WpT = (bf16*)(ws + (33ull << 20));

  const dim3 blk(256);

  // Prep: weight transposes + mask pack, one launch.
  prep_k<<<dim3(1280), blk, 0, stream>>>(Wq, Wkv, Wp, mask, BqkvT, WpT,
                                         maskbits);

  // Fused QKV projection: 24x64 = 1536 blocks (6/CU).
  gemm_sw<1><<<dim3(24, 64), blk, 0, stream>>>(x, context, nullptr, BqkvT, bq,
                                               bkv, qw, kw, vtw, nullptr);

  // Attention (aow overwrites dead BqkvT region).
  attn_kernel<<<dim3(16, 64), blk, 0, stream>>>(qw, kw, vtw, maskbits, aow);

  // Output projection: 8x64 = 512 blocks.
  gemm_sw<0><<<dim3(8, 64), blk, 0, stream>>>(nullptr, nullptr, aow, WpT, bp,
                                              nullptr, nullptr, nullptr,
                                              nullptr, out);
}

// Round 8
// 232.124 us; speedup vs baseline: 1.1604x; 1.0393x over previous
//
#include <hip/hip_runtime.h>

typedef __bf16 bf16;
typedef __bf16 bf16x8 __attribute__((ext_vector_type(8)));
typedef float f32x4 __attribute__((ext_vector_type(4)));
typedef unsigned long long u64;

#define MFMA16(a, b, c) __builtin_amdgcn_mfma_f32_16x16x32_bf16(a, b, c, 0, 0, 0)

// Async global->LDS, 16 B/lane; LDS dest = wave-uniform base + lane*16.
__device__ __forceinline__ void gl_lds16(const void* g, void* l) {
  __builtin_amdgcn_global_load_lds(
      (const __attribute__((address_space(1))) unsigned int*)g,
      (__attribute__((address_space(3))) unsigned int*)l, 16, 0, 0);
}

// ---------------------------------------------------------------------------
// Fused prep: blocks 0..1023 transpose+downcast weights (ct = bx>>4: 0..15 Wq,
// 16..47 Wkv -> BqkvT; 48..63 Wp -> WpT); blocks 1024..1279 pack the mask.
// ---------------------------------------------------------------------------
__global__ __launch_bounds__(256)
void prep_k(const float* __restrict__ Wq, const float* __restrict__ Wkv,
            const float* __restrict__ Wp, const int* __restrict__ mask,
            bf16* __restrict__ BqkvT, bf16* __restrict__ WpT,
            u64* __restrict__ maskbits) {
  const int bx = blockIdx.x;
  const int tid = threadIdx.x;
  if (bx >= 1024) {  // ---- mask pack: [4][1024][1024] i32 -> [4096][16] u64
    const int idx = (bx - 1024) * 256 + tid;
    const int4* p = (const int4*)(mask + (size_t)idx * 64);
    u64 v = 0;
#pragma unroll
    for (int i = 0; i < 16; ++i) {
      int4 m = p[i];
      v |= (u64)(m.x != 0) << (4 * i);
      v |= (u64)(m.y != 0) << (4 * i + 1);
      v |= (u64)(m.z != 0) << (4 * i + 2);
      v |= (u64)(m.w != 0) << (4 * i + 3);
    }
    maskbits[idx] = v;
    return;
  }
  // ---- weight transpose tile
  const int ct = bx >> 4, rt = bx & 15;
  const float* src;
  bf16* dst;
  int C, c0, drow0;
  if (ct < 16) {
    src = Wq; C = 1024; c0 = ct * 64; dst = BqkvT; drow0 = c0;
  } else if (ct < 48) {
    src = Wkv; C = 2048; c0 = (ct - 16) * 64; dst = BqkvT; drow0 = 1024 + c0;
  } else {
    src = Wp; C = 1024; c0 = (ct - 48) * 64; dst = WpT; drow0 = c0;
  }
  __shared__ bf16 T[64][72];
  const int r0 = rt * 64;
#pragma unroll
  for (int i = 0; i < 2; ++i) {
    int c = i * 256 + tid;
    int row = c >> 3, col = (c & 7) * 8;
    const float* sp = &src[(size_t)(r0 + row) * C + c0 + col];
    f32x4 a0 = *(const f32x4*)sp;
    f32x4 a1 = *(const f32x4*)(sp + 4);
    bf16x8 t;
#pragma unroll
    for (int j = 0; j < 4; ++j) { t[j] = (bf16)a0[j]; t[4 + j] = (bf16)a1[j]; }
    *(bf16x8*)&T[row][col] = t;
  }
  __syncthreads();
#pragma unroll
  for (int i = 0; i < 2; ++i) {
    int c = i * 256 + tid;
    int orow = c >> 3, ocol = (c & 7) * 8;
    bf16x8 v;
#pragma unroll
    for (int j = 0; j < 8; ++j) v[j] = T[ocol + j][orow];
    *(bf16x8*)&dst[(size_t)(drow0 + orow) * 1024 + r0 + ocol] = v;
  }
}

// ---------------------------------------------------------------------------
// Swizzled GEMM, 64(M)x128(N) tile, BK=64. XCD-aware grid: blockIdx.x =
// M-block so XCD = m%8 -> each XCD's L2 holds its 8 A-slabs (2 MB) for the
// whole kernel and the per-K-step B working set (384 KB). LDS unpadded
// [rows][64] with XOR column-block swizzle (conflict-free, round 7).
//   EPI 1 (QKV): A = f32 x/context (VGPR cvt, swizzled ds_write);
//                scatters Q*SCALE2 -> oq, K -> ok, V^T -> ovt.
//   EPI 0 (OP):  A = bf16 (async glds), writes f32 out.
// ---------------------------------------------------------------------------
template <int EPI>
__global__ __launch_bounds__(256)
void gemm_sw(const float* __restrict__ Af0, const float* __restrict__ Af1,
             const bf16* __restrict__ Ab, const bf16* __restrict__ Bt,
             const float* __restrict__ bias0, const float* __restrict__ bias1,
             bf16* __restrict__ oq, bf16* __restrict__ ok,
             bf16* __restrict__ ovt, float* __restrict__ outf) {
  __shared__ bf16 As[64][64];
  __shared__ bf16 Bs[128][64];
  const int tid = threadIdx.x;
  const int lane = tid & 63;
  const int w = tid >> 6;
  const int wm = (w >> 1) * 32, wn = (w & 1) * 64;
  const int l15 = lane & 15, l4 = lane >> 4;
  const int lrow = lane >> 3;
  const int scol = ((lane & 7) ^ (lrow & 7)) * 8;  // swizzled source column
  const int m0 = blockIdx.x * 64;   // m fastest -> XCD = m%8
  const int n0 = blockIdx.y * 128;

  const float* Asrc = (EPI == 1) ? ((n0 < 1024) ? Af0 : Af1) : nullptr;

  // f32 A staging coords (EPI 1): row ar, logical blocks acb, acb+1.
  const int ar = tid >> 2;
  const int acb = (tid & 3) * 2;

  f32x4 acc[2][4] = {};

  for (int kk = 0; kk < 1024; kk += 64) {
    // B tile (128x64): 4 async 1KB stages per wave.
#pragma unroll
    for (int it = 0; it < 4; ++it) {
      const int r = w * 32 + it * 8;
      gl_lds16(&Bt[(size_t)(n0 + r + lrow) * 1024 + kk + scol], &Bs[r][0]);
    }
    if (EPI == 0) {
#pragma unroll
      for (int it = 0; it < 2; ++it) {
        const int r = w * 16 + it * 8;
        gl_lds16(&Ab[(size_t)(m0 + r + lrow) * 1024 + kk + scol], &As[r][0]);
      }
    } else {
#pragma unroll
      for (int j = 0; j < 2; ++j) {
        const int cbL = acb + j;
        const float* ap = &Asrc[(size_t)(m0 + ar) * 1024 + kk + cbL * 8];
        f32x4 a0 = *(const f32x4*)ap;
        f32x4 a1 = *(const f32x4*)(ap + 4);
        bf16x8 t;
#pragma unroll
        for (int u = 0; u < 4; ++u) { t[u] = (bf16)a0[u]; t[4 + u] = (bf16)a1[u]; }
        *(bf16x8*)&As[ar][(cbL ^ (ar & 7)) * 8] = t;
      }
    }
    __syncthreads();
#pragma unroll
    for (int ks = 0; ks < 2; ++ks) {
      const int sw = ((ks * 4 + l4) ^ (l15 & 7)) * 8;  // physical col offset
      bf16x8 af[2], bfr[4];
#pragma unroll
      for (int i = 0; i < 2; ++i)
        af[i] = *(const bf16x8*)&As[wm + i * 16 + l15][sw];
#pragma unroll
      for (int j = 0; j < 4; ++j)
        bfr[j] = *(const bf16x8*)&Bs[wn + j * 16 + l15][sw];
#pragma unroll
      for (int i = 0; i < 2; ++i)
#pragma unroll
        for (int j = 0; j < 4; ++j)
          acc[i][j] = MFMA16(af[i], bfr[j], acc[i][j]);
    }
    __syncthreads();
  }

  const float SCALE2 = 0.18033688011112042f;  // 1/sqrt(64) * log2(e)
#pragma unroll
  for (int j = 0; j < 4; ++j) {
    const int col = n0 + wn + j * 16 + l15;
    float bc;
    if (EPI == 1) bc = (col < 1024) ? bias0[col] : bias1[col - 1024];
    else bc = bias0[col];
#pragma unroll
    for (int i = 0; i < 2; ++i) {
#pragma unroll
      for (int r = 0; r < 4; ++r) {
        const int row = m0 + wm + i * 16 + l4 * 4 + r;
        const float v = acc[i][j][r] + bc;
        if (EPI == 0) {
          outf[(size_t)row * 1024 + col] = v;
        } else {
          const int b = row >> 10, n = row & 1023;
          if (col < 1024) {
            const int h = col >> 6, d = col & 63;
            oq[(((size_t)(b * 16 + h)) * 1024 + n) * 64 + d] =
                (bf16)(v * SCALE2);
          } else {
            const int ckv = col - 1024;
            const int s = ckv >> 10, c2 = ckv & 1023;
            const int h = c2 >> 6, d = c2 & 63;
            if (s == 0)
              ok[(((size_t)(b * 16 + h)) * 1024 + n) * 64 + d] = (bf16)v;
            else
              ovt[(((size_t)(b * 16 + h)) * 64 + d) * 1024 + n] = (bf16)v;
          }
        }
      }
    }
  }
}

// ---------------------------------------------------------------------------
// Flash-style masked attention, fixed-max softmax, bit-packed mask.
// XCD-aware grid: blockIdx.x = bh -> XCD = bh%8; each XCD's L2 holds its
// 8 heads' K+V (2 MB) across all 16 n-tile blocks.
// ---------------------------------------------------------------------------
__global__ __launch_bounds__(256)
void attn_kernel(const bf16* __restrict__ q, const bf16* __restrict__ k,
                 const bf16* __restrict__ vT, const u64* __restrict__ maskbits,
                 bf16* __restrict__ ao) {
  const int bh = blockIdx.x;      // bh fastest -> XCD = bh%8
  const int ntile = blockIdx.y;
  const int b = bh >> 4, h = bh & 15;
  const int tid = threadIdx.x;
  const int lane = tid & 63;
  const int w = tid >> 6;
  const int l15 = lane & 15, l4 = lane >> 4;

  __shared__ bf16 Ks[64][72];
  __shared__ bf16 Vts[64][72];
  __shared__ bf16 Pw[4][16][72];

  const size_t base = (size_t)bh * 65536;
  const int nrow0 = ntile * 64 + w * 16;

  bf16x8 qf[2];
#pragma unroll
  for (int ks = 0; ks < 2; ++ks)
    qf[ks] =
        *(const bf16x8*)&q[base + (size_t)(nrow0 + l15) * 64 + ks * 32 + l4 * 8];

  f32x4 o[4] = {};
  float lsum[4] = {0.0f, 0.0f, 0.0f, 0.0f};

  const u64* mb = maskbits + (size_t)(b * 1024 + nrow0) * 16;

  for (int mt = 0; mt < 16; ++mt) {
#pragma unroll
    for (int i = 0; i < 2; ++i) {
      int c = i * 256 + tid;
      int row = c >> 3, col = (c & 7) * 8;
      *(bf16x8*)&Ks[row][col] =
          *(const bf16x8*)&k[base + (size_t)(mt * 64 + row) * 64 + col];
      *(bf16x8*)&Vts[row][col] =
          *(const bf16x8*)&vT[base + (size_t)row * 1024 + mt * 64 + col];
    }
    __syncthreads();

    f32x4 s[4];
#pragma unroll
    for (int sub = 0; sub < 4; ++sub) s[sub] = f32x4{-12.f, -12.f, -12.f, -12.f};
#pragma unroll
    for (int ks = 0; ks < 2; ++ks) {
#pragma unroll
      for (int sub = 0; sub < 4; ++sub) {
        bf16x8 bfr = *(const bf16x8*)&Ks[sub * 16 + l15][ks * 32 + l4 * 8];
        s[sub] = MFMA16(qf[ks], bfr, s[sub]);
      }
    }

    u64 wbits[4];
#pragma unroll
    for (int r = 0; r < 4; ++r) wbits[r] = mb[(size_t)(l4 * 4 + r) * 16 + mt];

#pragma unroll
    for (int sub = 0; sub < 4; ++sub) {
#pragma unroll
      for (int r = 0; r < 4; ++r) {
        float p = exp2f(s[sub][r]);
        p = ((wbits[r] >> (sub * 16 + l15)) & 1) ? p : 0.0f;
        lsum[r] += p;
        Pw[w][l4 * 4 + r][sub * 16 + l15] = (bf16)p;
      }
    }

#pragma unroll
    for (int ks = 0; ks < 2; ++ks) {
      bf16x8 af = *(const bf16x8*)&Pw[w][l15][ks * 32 + l4 * 8];
#pragma unroll
      for (int sub = 0; sub < 4; ++sub) {
        bf16x8 bfr = *(const bf16x8*)&Vts[sub * 16 + l15][ks * 32 + l4 * 8];
        o[sub] = MFMA16(af, bfr, o[sub]);
      }
    }
    __syncthreads();
  }

  float inv[4];
#pragma unroll
  for (int r = 0; r < 4; ++r) {
    float t = lsum[r];
#pragma unroll
    for (int d = 1; d < 16; d <<= 1) t += __shfl_xor(t, d);
    inv[r] = 1.0f / t;
  }

#pragma unroll
  for (int sub = 0; sub < 4; ++sub) {
#pragma unroll
    for (int r = 0; r < 4; ++r) {
      const int n = nrow0 + l4 * 4 + r;
      const size_t idx =
          ((size_t)(b * 1024 + n)) * 1024 + h * 64 + sub * 16 + l15;
      ao[idx] = (bf16)(o[sub][r] * inv[r]);
    }
  }
}

// ---------------------------------------------------------------------------
extern "C" void kernel_launch(void* const* d_in, const int* in_sizes, int n_in,
                              void* d_out, int out_size, void* d_ws,
                              size_t ws_size, hipStream_t stream) {
  const float* x = (const float*)d_in[0];        // [4,1024,1024]
  const float* context = (const float*)d_in[1];  // [4,1024,1024]
  const int* mask = (const int*)d_in[2];         // [4,1024,32,32]
  const float* Wq = (const float*)d_in[3];
  const float* bq = (const float*)d_in[4];
  const float* Wkv = (const float*)d_in[5];
  const float* bkv = (const float*)d_in[6];
  const float* Wp = (const float*)d_in[7];
  const float* bp = (const float*)d_in[8];
  float* out = (float*)d_out;                    // [4,1024,1024] f32

  // Workspace (35 MB):
  //  @0  (6 MB): BqkvT  -> dead after QKV; aow (8 MB @0) overwrites it
  //  @8  (8 MB): qw   @16 (8 MB): kw   @24 (8 MB): vtw
  //  @32 (0.5 MB): maskbits   @33 (2 MB): WpT
  char* ws = (char*)d_ws;
  bf16* BqkvT = (bf16*)(ws);
  bf16* aow = (bf16*)(ws);
  bf16* qw = (bf16*)(ws + (8ull << 20));
  bf16* kw = (bf16*)(ws + (16ull << 20));
  bf16* vtw = (bf16*)(ws + (24ull << 20));
  u64* maskbits = (u64*)(ws + (32ull << 20));
  bf16* WpT = (bf16*)(ws + (33ull << 20));

  const dim3 blk(256);

  // Prep: weight transposes + mask pack, one launch.
  prep_k<<<dim3(1280), blk, 0, stream>>>(Wq, Wkv, Wp, mask, BqkvT, WpT,
                                         maskbits);

  // Fused QKV projection: grid (m=64, n=24) -> XCD = m%8.
  gemm_sw<1><<<dim3(64, 24), blk, 0, stream>>>(x, context, nullptr, BqkvT, bq,
                                               bkv, qw, kw, vtw, nullptr);

  // Attention: grid (bh=64, ntile=16) -> XCD = bh%8.
  attn_kernel<<<dim3(64, 16), blk, 0, stream>>>(qw, kw, vtw, maskbits, aow);

  // Output projection: grid (m=64, n=8) -> XCD = m%8.
  gemm_sw<0><<<dim3(64, 8), blk, 0, stream>>>(nullptr, nullptr, aow, WpT, bp,
                                              nullptr, nullptr, nullptr,
                                              nullptr, out);
}

// Round 9
// 231.407 us; speedup vs baseline: 1.1640x; 1.0031x over previous
//
#include <hip/hip_runtime.h>

typedef __bf16 bf16;
typedef __bf16 bf16x8 __attribute__((ext_vector_type(8)));
typedef float f32x4 __attribute__((ext_vector_type(4)));
typedef unsigned long long u64;

#define MFMA16(a, b, c) __builtin_amdgcn_mfma_f32_16x16x32_bf16(a, b, c, 0, 0, 0)

// Async global->LDS, 16 B/lane; LDS dest = wave-uniform base + lane*16.
__device__ __forceinline__ void gl_lds16(const void* g, void* l) {
  __builtin_amdgcn_global_load_lds(
      (const __attribute__((address_space(1))) unsigned int*)g,
      (__attribute__((address_space(3))) unsigned int*)l, 16, 0, 0);
}

// ---------------------------------------------------------------------------
// Fused prep:
//   blocks    0..1023: weight transpose+downcast (Wq,Wkv -> BqkvT; Wp -> WpT)
//   blocks 1024..1279: mask pack -> u64 bit-words
//   blocks 1280..3327: context f32 -> bf16 (cb)
// ---------------------------------------------------------------------------
__global__ __launch_bounds__(256)
void prep_k(const float* __restrict__ Wq, const float* __restrict__ Wkv,
            const float* __restrict__ Wp, const int* __restrict__ mask,
            const float* __restrict__ context, bf16* __restrict__ BqkvT,
            bf16* __restrict__ WpT, u64* __restrict__ maskbits,
            bf16* __restrict__ cb) {
  const int bx = blockIdx.x;
  const int tid = threadIdx.x;
  if (bx >= 1280) {  // ---- context downcast
    const size_t i = ((size_t)(bx - 1280) * 256 + tid) * 8;
    f32x4 a0 = *(const f32x4*)(context + i);
    f32x4 a1 = *(const f32x4*)(context + i + 4);
    bf16x8 t;
#pragma unroll
    for (int j = 0; j < 4; ++j) { t[j] = (bf16)a0[j]; t[4 + j] = (bf16)a1[j]; }
    *(bf16x8*)(cb + i) = t;
    return;
  }
  if (bx >= 1024) {  // ---- mask pack
    const int idx = (bx - 1024) * 256 + tid;
    const int4* p = (const int4*)(mask + (size_t)idx * 64);
    u64 v = 0;
#pragma unroll
    for (int i = 0; i < 16; ++i) {
      int4 m = p[i];
      v |= (u64)(m.x != 0) << (4 * i);
      v |= (u64)(m.y != 0) << (4 * i + 1);
      v |= (u64)(m.z != 0) << (4 * i + 2);
      v |= (u64)(m.w != 0) << (4 * i + 3);
    }
    maskbits[idx] = v;
    return;
  }
  // ---- weight transpose tile
  const int ct = bx >> 4, rt = bx & 15;
  const float* src;
  bf16* dst;
  int C, c0, drow0;
  if (ct < 16) {
    src = Wq; C = 1024; c0 = ct * 64; dst = BqkvT; drow0 = c0;
  } else if (ct < 48) {
    src = Wkv; C = 2048; c0 = (ct - 16) * 64; dst = BqkvT; drow0 = 1024 + c0;
  } else {
    src = Wp; C = 1024; c0 = (ct - 48) * 64; dst = WpT; drow0 = c0;
  }
  __shared__ bf16 T[64][72];
  const int r0 = rt * 64;
#pragma unroll
  for (int i = 0; i < 2; ++i) {
    int c = i * 256 + tid;
    int row = c >> 3, col = (c & 7) * 8;
    const float* sp = &src[(size_t)(r0 + row) * C + c0 + col];
    f32x4 a0 = *(const f32x4*)sp;
    f32x4 a1 = *(const f32x4*)(sp + 4);
    bf16x8 t;
#pragma unroll
    for (int j = 0; j < 4; ++j) { t[j] = (bf16)a0[j]; t[4 + j] = (bf16)a1[j]; }
    *(bf16x8*)&T[row][col] = t;
  }
  __syncthreads();
#pragma unroll
  for (int i = 0; i < 2; ++i) {
    int c = i * 256 + tid;
    int orow = c >> 3, ocol = (c & 7) * 8;
    bf16x8 v;
#pragma unroll
    for (int j = 0; j < 8; ++j) v[j] = T[ocol + j][orow];
    *(bf16x8*)&dst[(size_t)(drow0 + orow) * 1024 + r0 + ocol] = v;
  }
}

// ---------------------------------------------------------------------------
// QKV GEMM, m97 shape: 128x128 tile, BK=64, 4 waves each 64x64 (4x4 MFMA
// subtiles, 32 MFMA/K-iter). XOR-swizzled unpadded LDS (0 conflicts), XCD
// grid (blockIdx.x = m-block -> XCD = m%8). KV-side A (cb, bf16) and B via
// global_load_lds; Q-side A from f32 x via VGPR cvt + swizzled ds_write.
// grid (32, 24) = 768 blocks = 3/CU.
// ---------------------------------------------------------------------------
__global__ __launch_bounds__(256)
void gemm_qkv128(const float* __restrict__ xf, const bf16* __restrict__ cb,
                 const bf16* __restrict__ Bt, const float* __restrict__ bq,
                 const float* __restrict__ bkv, bf16* __restrict__ oq,
                 bf16* __restrict__ ok, bf16* __restrict__ ovt) {
  __shared__ bf16 As[128][64];
  __shared__ bf16 Bs[128][64];
  const int tid = threadIdx.x;
  const int lane = tid & 63;
  const int w = tid >> 6;
  const int wm = (w >> 1) * 64, wn = (w & 1) * 64;
  const int l15 = lane & 15, l4 = lane >> 4;
  const int lrow = lane >> 3;
  const int scol = ((lane & 7) ^ (lrow & 7)) * 8;
  const int m0 = blockIdx.x * 128;  // m fastest -> XCD = m%8
  const int n0 = blockIdx.y * 128;
  const bool qside = (n0 < 1024);

  // Q-side f32 staging: 2 threads/row, 32 f32 each (4 logical 8-elem blocks).
  const int ar = tid >> 1;
  const int albase = (tid & 1) * 4;

  f32x4 acc[4][4] = {};

  for (int kk = 0; kk < 1024; kk += 64) {
#pragma unroll
    for (int it = 0; it < 4; ++it) {
      const int r = w * 32 + it * 8;
      gl_lds16(&Bt[(size_t)(n0 + r + lrow) * 1024 + kk + scol], &Bs[r][0]);
    }
    if (qside) {
#pragma unroll
      for (int j = 0; j < 4; ++j) {
        const int lb = albase + j;
        const float* ap = &xf[(size_t)(m0 + ar) * 1024 + kk + lb * 8];
        f32x4 a0 = *(const f32x4*)ap;
        f32x4 a1 = *(const f32x4*)(ap + 4);
        bf16x8 t;
#pragma unroll
        for (int u = 0; u < 4; ++u) { t[u] = (bf16)a0[u]; t[4 + u] = (bf16)a1[u]; }
        *(bf16x8*)&As[ar][(lb ^ (ar & 7)) * 8] = t;
      }
    } else {
#pragma unroll
      for (int it = 0; it < 4; ++it) {
        const int r = w * 32 + it * 8;
        gl_lds16(&cb[(size_t)(m0 + r + lrow) * 1024 + kk + scol], &As[r][0]);
      }
    }
    __syncthreads();
#pragma unroll
    for (int ks = 0; ks < 2; ++ks) {
      const int sw = ((ks * 4 + l4) ^ (l15 & 7)) * 8;
      bf16x8 af[4], bfr[4];
#pragma unroll
      for (int i = 0; i < 4; ++i)
        af[i] = *(const bf16x8*)&As[wm + i * 16 + l15][sw];
#pragma unroll
      for (int j = 0; j < 4; ++j)
        bfr[j] = *(const bf16x8*)&Bs[wn + j * 16 + l15][sw];
#pragma unroll
      for (int i = 0; i < 4; ++i)
#pragma unroll
        for (int j = 0; j < 4; ++j)
          acc[i][j] = MFMA16(af[i], bfr[j], acc[i][j]);
    }
    __syncthreads();
  }

  const float SCALE2 = 0.18033688011112042f;  // 1/sqrt(64) * log2(e)
#pragma unroll
  for (int j = 0; j < 4; ++j) {
    const int col = n0 + wn + j * 16 + l15;
    const float bc = (col < 1024) ? bq[col] : bkv[col - 1024];
#pragma unroll
    for (int i = 0; i < 4; ++i) {
#pragma unroll
      for (int r = 0; r < 4; ++r) {
        const int row = m0 + wm + i * 16 + l4 * 4 + r;
        const float v = acc[i][j][r] + bc;
        const int b = row >> 10, n = row & 1023;
        if (col < 1024) {
          const int h = col >> 6, d = col & 63;
          oq[(((size_t)(b * 16 + h)) * 1024 + n) * 64 + d] = (bf16)(v * SCALE2);
        } else {
          const int ckv = col - 1024;
          const int s = ckv >> 10, c2 = ckv & 1023;
          const int h = c2 >> 6, d = c2 & 63;
          if (s == 0)
            ok[(((size_t)(b * 16 + h)) * 1024 + n) * 64 + d] = (bf16)v;
          else
            ovt[(((size_t)(b * 16 + h)) * 64 + d) * 1024 + n] = (bf16)v;
        }
      }
    }
  }
}

// ---------------------------------------------------------------------------
// Output projection: 64x128 tile, all-bf16 glds staging, swizzled LDS, XCD
// grid (m fastest). grid (64, 8) = 512 blocks. Writes f32.
// ---------------------------------------------------------------------------
__global__ __launch_bounds__(256)
void gemm_op(const bf16* __restrict__ Ab, const bf16* __restrict__ Bt,
             const float* __restrict__ bias, float* __restrict__ outf) {
  __shared__ bf16 As[64][64];
  __shared__ bf16 Bs[128][64];
  const int tid = threadIdx.x;
  const int lane = tid & 63;
  const int w = tid >> 6;
  const int wm = (w >> 1) * 32, wn = (w & 1) * 64;
  const int l15 = lane & 15, l4 = lane >> 4;
  const int lrow = lane >> 3;
  const int scol = ((lane & 7) ^ (lrow & 7)) * 8;
  const int m0 = blockIdx.x * 64;
  const int n0 = blockIdx.y * 128;

  f32x4 acc[2][4] = {};

  for (int kk = 0; kk < 1024; kk += 64) {
#pragma unroll
    for (int it = 0; it < 4; ++it) {
      const int r = w * 32 + it * 8;
      gl_lds16(&Bt[(size_t)(n0 + r + lrow) * 1024 + kk + scol], &Bs[r][0]);
    }
#pragma unroll
    for (int it = 0; it < 2; ++it) {
      const int r = w * 16 + it * 8;
      gl_lds16(&Ab[(size_t)(m0 + r + lrow) * 1024 + kk + scol], &As[r][0]);
    }
    __syncthreads();
#pragma unroll
    for (int ks = 0; ks < 2; ++ks) {
      const int sw = ((ks * 4 + l4) ^ (l15 & 7)) * 8;
      bf16x8 af[2], bfr[4];
#pragma unroll
      for (int i = 0; i < 2; ++i)
        af[i] = *(const bf16x8*)&As[wm + i * 16 + l15][sw];
#pragma unroll
      for (int j = 0; j < 4; ++j)
        bfr[j] = *(const bf16x8*)&Bs[wn + j * 16 + l15][sw];
#pragma unroll
      for (int i = 0; i < 2; ++i)
#pragma unroll
        for (int j = 0; j < 4; ++j)
          acc[i][j] = MFMA16(af[i], bfr[j], acc[i][j]);
    }
    __syncthreads();
  }

#pragma unroll
  for (int j = 0; j < 4; ++j) {
    const int col = n0 + wn + j * 16 + l15;
    const float bc = bias[col];
#pragma unroll
    for (int i = 0; i < 2; ++i) {
#pragma unroll
      for (int r = 0; r < 4; ++r) {
        const int row = m0 + wm + i * 16 + l4 * 4 + r;
        outf[(size_t)row * 1024 + col] = acc[i][j][r] + bc;
      }
    }
  }
}

// ---------------------------------------------------------------------------
// Flash-style masked attention, fixed-max softmax, bit-packed mask, XCD grid
// (bh fastest). Unchanged from round 8.
// ---------------------------------------------------------------------------
__global__ __launch_bounds__(256)
void attn_kernel(const bf16* __restrict__ q, const bf16* __restrict__ k,
                 const bf16* __restrict__ vT, const u64* __restrict__ maskbits,
                 bf16* __restrict__ ao) {
  const int bh = blockIdx.x;
  const int ntile = blockIdx.y;
  const int b = bh >> 4, h = bh & 15;
  const int tid = threadIdx.x;
  const int lane = tid & 63;
  const int w = tid >> 6;
  const int l15 = lane & 15, l4 = lane >> 4;

  __shared__ bf16 Ks[64][72];
  __shared__ bf16 Vts[64][72];
  __shared__ bf16 Pw[4][16][72];

  const size_t base = (size_t)bh * 65536;
  const int nrow0 = ntile * 64 + w * 16;

  bf16x8 qf[2];
#pragma unroll
  for (int ks = 0; ks < 2; ++ks)
    qf[ks] =
        *(const bf16x8*)&q[base + (size_t)(nrow0 + l15) * 64 + ks * 32 + l4 * 8];

  f32x4 o[4] = {};
  float lsum[4] = {0.0f, 0.0f, 0.0f, 0.0f};

  const u64* mb = maskbits + (size_t)(b * 1024 + nrow0) * 16;

  for (int mt = 0; mt < 16; ++mt) {
#pragma unroll
    for (int i = 0; i < 2; ++i) {
      int c = i * 256 + tid;
      int row = c >> 3, col = (c & 7) * 8;
      *(bf16x8*)&Ks[row][col] =
          *(const bf16x8*)&k[base + (size_t)(mt * 64 + row) * 64 + col];
      *(bf16x8*)&Vts[row][col] =
          *(const bf16x8*)&vT[base + (size_t)row * 1024 + mt * 64 + col];
    }
    __syncthreads();

    f32x4 s[4];
#pragma unroll
    for (int sub = 0; sub < 4; ++sub) s[sub] = f32x4{-12.f, -12.f, -12.f, -12.f};
#pragma unroll
    for (int ks = 0; ks < 2; ++ks) {
#pragma unroll
      for (int sub = 0; sub < 4; ++sub) {
        bf16x8 bfr = *(const bf16x8*)&Ks[sub * 16 + l15][ks * 32 + l4 * 8];
        s[sub] = MFMA16(qf[ks], bfr, s[sub]);
      }
    }

    u64 wbits[4];
#pragma unroll
    for (int r = 0; r < 4; ++r) wbits[r] = mb[(size_t)(l4 * 4 + r) * 16 + mt];

#pragma unroll
    for (int sub = 0; sub < 4; ++sub) {
#pragma unroll
      for (int r = 0; r < 4; ++r) {
        float p = exp2f(s[sub][r]);
        p = ((wbits[r] >> (sub * 16 + l15)) & 1) ? p : 0.0f;
        lsum[r] += p;
        Pw[w][l4 * 4 + r][sub * 16 + l15] = (bf16)p;
      }
    }

#pragma unroll
    for (int ks = 0; ks < 2; ++ks) {
      bf16x8 af = *(const bf16x8*)&Pw[w][l15][ks * 32 + l4 * 8];
#pragma unroll
      for (int sub = 0; sub < 4; ++sub) {
        bf16x8 bfr = *(const bf16x8*)&Vts[sub * 16 + l15][ks * 32 + l4 * 8];
        o[sub] = MFMA16(af, bfr, o[sub]);
      }
    }
    __syncthreads();
  }

  float inv[4];
#pragma unroll
  for (int r = 0; r < 4; ++r) {
    float t = lsum[r];
#pragma unroll
    for (int d = 1; d < 16; d <<= 1) t += __shfl_xor(t, d);
    inv[r] = 1.0f / t;
  }

#pragma unroll
  for (int sub = 0; sub < 4; ++sub) {
#pragma unroll
    for (int r = 0; r < 4; ++r) {
      const int n = nrow0 + l4 * 4 + r;
      const size_t idx =
          ((size_t)(b * 1024 + n)) * 1024 + h * 64 + sub * 16 + l15;
      ao[idx] = (bf16)(o[sub][r] * inv[r]);
    }
  }
}

// ---------------------------------------------------------------------------
extern "C" void kernel_launch(void* const* d_in, const int* in_sizes, int n_in,
                              void* d_out, int out_size, void* d_ws,
                              size_t ws_size, hipStream_t stream) {
  const float* x = (const float*)d_in[0];        // [4,1024,1024]
  const float* context = (const float*)d_in[1];  // [4,1024,1024]
  const int* mask = (const int*)d_in[2];         // [4,1024,32,32]
  const float* Wq = (const float*)d_in[3];
  const float* bq = (const float*)d_in[4];
  const float* Wkv = (const float*)d_in[5];
  const float* bkv = (const float*)d_in[6];
  const float* Wp = (const float*)d_in[7];
  const float* bp = (const float*)d_in[8];
  float* out = (float*)d_out;                    // [4,1024,1024] f32

  // Workspace (40.5 MB):
  //  @0    (8 MB): cb (prep->QKV), dead after QKV -> aow reuses it
  //  @8    (6 MB): BqkvT (prep->QKV)
  //  @14   (8 MB): qw   @22 (8 MB): kw   @30 (8 MB): vtw
  //  @38 (0.5 MB): maskbits   @38.5 (2 MB): WpT
  char* ws = (char*)d_ws;
  bf16* cb = (bf16*)(ws);
  bf16* aow = (bf16*)(ws);
  bf16* BqkvT = (bf16*)(ws + (8ull << 20));
  bf16* qw = (bf16*)(ws + (14ull << 20));
  bf16* kw = (bf16*)(ws + (22ull << 20));
  bf16* vtw = (bf16*)(ws + (30ull << 20));
  u64* maskbits = (u64*)(ws + (38ull << 20));
  bf16* WpT = (bf16*)(ws + (38ull << 20) + (512ull << 10));

  const dim3 blk(256);

  // Prep: weight transposes + mask pack + context downcast, one launch.
  prep_k<<<dim3(3328), blk, 0, stream>>>(Wq, Wkv, Wp, mask, context, BqkvT,
                                         WpT, maskbits, cb);

  // Fused QKV projection: 128x128 tiles, grid (m=32, n=24) -> XCD = m%8.
  gemm_qkv128<<<dim3(32, 24), blk, 0, stream>>>(x, cb, BqkvT, bq, bkv, qw, kw,
                                                vtw);

  // Attention: grid (bh=64, ntile=16) -> XCD = bh%8.
  attn_kernel<<<dim3(64, 16), blk, 0, stream>>>(qw, kw, vtw, maskbits, aow);

  // Output projection: grid (m=64, n=8) -> XCD = m%8.
  gemm_op<<<dim3(64, 8), blk, 0, stream>>>(aow, WpT, bp, out);
}

// Round 10
// 230.661 us; speedup vs baseline: 1.1677x; 1.0032x over previous
//
#include <hip/hip_runtime.h>

typedef __bf16 bf16;
typedef __bf16 bf16x8 __attribute__((ext_vector_type(8)));
typedef float f32x4 __attribute__((ext_vector_type(4)));
typedef unsigned long long u64;

#define MFMA16(a, b, c) __builtin_amdgcn_mfma_f32_16x16x32_bf16(a, b, c, 0, 0, 0)

// Async global->LDS, 16 B/lane; LDS dest = wave-uniform base + lane*16.
__device__ __forceinline__ void gl_lds16(const void* g, void* l) {
  __builtin_amdgcn_global_load_lds(
      (const __attribute__((address_space(1))) unsigned int*)g,
      (__attribute__((address_space(3))) unsigned int*)l, 16, 0, 0);
}

// ---------------------------------------------------------------------------
// Fused prep:
//   blocks    0..1023: weight transpose+downcast (Wq,Wkv -> BqkvT; Wp -> WpT)
//   blocks 1024..1279: mask pack -> u64 bit-words
//   blocks 1280..3327: context f32 -> bf16 (cb)
// ---------------------------------------------------------------------------
__global__ __launch_bounds__(256)
void prep_k(const float* __restrict__ Wq, const float* __restrict__ Wkv,
            const float* __restrict__ Wp, const int* __restrict__ mask,
            const float* __restrict__ context, bf16* __restrict__ BqkvT,
            bf16* __restrict__ WpT, u64* __restrict__ maskbits,
            bf16* __restrict__ cb) {
  const int bx = blockIdx.x;
  const int tid = threadIdx.x;
  if (bx >= 1280) {  // ---- context downcast
    const size_t i = ((size_t)(bx - 1280) * 256 + tid) * 8;
    f32x4 a0 = *(const f32x4*)(context + i);
    f32x4 a1 = *(const f32x4*)(context + i + 4);
    bf16x8 t;
#pragma unroll
    for (int j = 0; j < 4; ++j) { t[j] = (bf16)a0[j]; t[4 + j] = (bf16)a1[j]; }
    *(bf16x8*)(cb + i) = t;
    return;
  }
  if (bx >= 1024) {  // ---- mask pack
    const int idx = (bx - 1024) * 256 + tid;
    const int4* p = (const int4*)(mask + (size_t)idx * 64);
    u64 v = 0;
#pragma unroll
    for (int i = 0; i < 16; ++i) {
      int4 m = p[i];
      v |= (u64)(m.x != 0) << (4 * i);
      v |= (u64)(m.y != 0) << (4 * i + 1);
      v |= (u64)(m.z != 0) << (4 * i + 2);
      v |= (u64)(m.w != 0) << (4 * i + 3);
    }
    maskbits[idx] = v;
    return;
  }
  // ---- weight transpose tile
  const int ct = bx >> 4, rt = bx & 15;
  const float* src;
  bf16* dst;
  int C, c0, drow0;
  if (ct < 16) {
    src = Wq; C = 1024; c0 = ct * 64; dst = BqkvT; drow0 = c0;
  } else if (ct < 48) {
    src = Wkv; C = 2048; c0 = (ct - 16) * 64; dst = BqkvT; drow0 = 1024 + c0;
  } else {
    src = Wp; C = 1024; c0 = (ct - 48) * 64; dst = WpT; drow0 = c0;
  }
  __shared__ bf16 T[64][72];
  const int r0 = rt * 64;
#pragma unroll
  for (int i = 0; i < 2; ++i) {
    int c = i * 256 + tid;
    int row = c >> 3, col = (c & 7) * 8;
    const float* sp = &src[(size_t)(r0 + row) * C + c0 + col];
    f32x4 a0 = *(const f32x4*)sp;
    f32x4 a1 = *(const f32x4*)(sp + 4);
    bf16x8 t;
#pragma unroll
    for (int j = 0; j < 4; ++j) { t[j] = (bf16)a0[j]; t[4 + j] = (bf16)a1[j]; }
    *(bf16x8*)&T[row][col] = t;
  }
  __syncthreads();
#pragma unroll
  for (int i = 0; i < 2; ++i) {
    int c = i * 256 + tid;
    int orow = c >> 3, ocol = (c & 7) * 8;
    bf16x8 v;
#pragma unroll
    for (int j = 0; j < 8; ++j) v[j] = T[ocol + j][orow];
    *(bf16x8*)&dst[(size_t)(drow0 + orow) * 1024 + r0 + ocol] = v;
  }
}

// ---------------------------------------------------------------------------
// Double-buffered GEMM, 64(M)x128(N) tile, BK=64, single barrier per K-iter:
// tile k+1's global_load_lds is issued right after the barrier and stays in
// flight across tile k's MFMA block, draining at the next barrier. As/Bs both
// double-buffered (48 KB -> 3 blocks/CU). XOR-swizzled LDS (0 conflicts),
// XCD grid (blockIdx.x = m-block -> XCD = m%8).
//   EPI 1 (QKV): kv-side A = cb (bf16, async); q-side A = x f32 (early vector
//                loads -> cvt+ds_write after MFMAs). Scatters Q*SCALE2/K/V^T.
//   EPI 0 (OP):  A = bf16 (async), writes f32 out.
// ---------------------------------------------------------------------------
template <int EPI>
__global__ __launch_bounds__(256)
void gemm_db(const float* __restrict__ Af0, const float* __restrict__ Af1,
             const bf16* __restrict__ Ab, const bf16* __restrict__ Bt,
             const float* __restrict__ bias0, const float* __restrict__ bias1,
             bf16* __restrict__ oq, bf16* __restrict__ ok,
             bf16* __restrict__ ovt, float* __restrict__ outf) {
  __shared__ bf16 As[2][64][64];
  __shared__ bf16 Bs[2][128][64];
  const int tid = threadIdx.x;
  const int lane = tid & 63;
  const int w = tid >> 6;
  const int wm = (w >> 1) * 32, wn = (w & 1) * 64;
  const int l15 = lane & 15, l4 = lane >> 4;
  const int lrow = lane >> 3;
  const int scol = ((lane & 7) ^ (lrow & 7)) * 8;  // swizzled source column
  const int m0 = blockIdx.x * 64;   // m fastest -> XCD = m%8
  const int n0 = blockIdx.y * 128;

  const bool a_async = (EPI == 0) || (n0 >= 1024);
  const float* Af = (EPI == 1) ? ((n0 < 1024) ? Af0 : Af1) : nullptr;
  const bf16* Asrc = (EPI == 0) ? Ab : ((const bf16*)Af1);  // cb for kv-side

  // f32 A staging coords: 4 threads/row, 16 f32 each (2 logical 8-blocks).
  const int ar = tid >> 2;
  const int acb = (tid & 3) * 2;

  f32x4 pf[4];
  f32x4 acc[2][4] = {};

#define STAGE_B(kk, buf)                                                      \
  _Pragma("unroll") for (int it = 0; it < 4; ++it) {                          \
    const int r = w * 32 + it * 8;                                            \
    gl_lds16(&Bt[(size_t)(n0 + r + lrow) * 1024 + (kk) + scol],               \
             &Bs[buf][r][0]);                                                 \
  }
#define STAGE_A_ASYNC(kk, buf)                                                \
  _Pragma("unroll") for (int it = 0; it < 2; ++it) {                          \
    const int r = w * 16 + it * 8;                                            \
    gl_lds16(&Asrc[(size_t)(m0 + r + lrow) * 1024 + (kk) + scol],             \
             &As[buf][r][0]);                                                 \
  }
#define LOAD_A_F32(kk)                                                        \
  {                                                                           \
    const float* ap = &Af[(size_t)(m0 + ar) * 1024 + (kk) + acb * 8];         \
    pf[0] = *(const f32x4*)ap;                                                \
    pf[1] = *(const f32x4*)(ap + 4);                                          \
    pf[2] = *(const f32x4*)(ap + 8);                                          \
    pf[3] = *(const f32x4*)(ap + 12);                                         \
  }
#define COMMIT_A_F32(buf)                                                     \
  _Pragma("unroll") for (int j = 0; j < 2; ++j) {                             \
    bf16x8 t;                                                                 \
    _Pragma("unroll") for (int u = 0; u < 4; ++u) {                           \
      t[u] = (bf16)pf[2 * j][u];                                              \
      t[4 + u] = (bf16)pf[2 * j + 1][u];                                      \
    }                                                                         \
    *(bf16x8*)&As[buf][ar][((acb + j) ^ (ar & 7)) * 8] = t;                   \
  }

  // Prologue: stage tile 0 into buffer 0.
  STAGE_B(0, 0);
  if (a_async) {
    STAGE_A_ASYNC(0, 0);
  } else {
    LOAD_A_F32(0);
    COMMIT_A_F32(0);
  }

  for (int k = 0; k < 16; ++k) {
    const int cur = k & 1, nxt = cur ^ 1;
    if (!a_async && k < 15) LOAD_A_F32((k + 1) * 64);  // max flight time
    __syncthreads();  // drains tile k staging (vmcnt+lgkm)
    if (k < 15) {
      STAGE_B((k + 1) * 64, nxt);
      if (a_async) STAGE_A_ASYNC((k + 1) * 64, nxt);
    }
#pragma unroll
    for (int ks = 0; ks < 2; ++ks) {
      const int sw = ((ks * 4 + l4) ^ (l15 & 7)) * 8;
      bf16x8 af[2], bfr[4];
#pragma unroll
      for (int i = 0; i < 2; ++i)
        af[i] = *(const bf16x8*)&As[cur][wm + i * 16 + l15][sw];
#pragma unroll
      for (int j = 0; j < 4; ++j)
        bfr[j] = *(const bf16x8*)&Bs[cur][wn + j * 16 + l15][sw];
#pragma unroll
      for (int i = 0; i < 2; ++i)
#pragma unroll
        for (int j = 0; j < 4; ++j)
          acc[i][j] = MFMA16(af[i], bfr[j], acc[i][j]);
    }
    if (!a_async && k < 15) COMMIT_A_F32(nxt);  // loads waited here, post-MFMA
  }

  const float SCALE2 = 0.18033688011112042f;  // 1/sqrt(64) * log2(e)
#pragma unroll
  for (int j = 0; j < 4; ++j) {
    const int col = n0 + wn + j * 16 + l15;
    float bc;
    if (EPI == 1) bc = (col < 1024) ? bias0[col] : bias1[col - 1024];
    else bc = bias0[col];
#pragma unroll
    for (int i = 0; i < 2; ++i) {
#pragma unroll
      for (int r = 0; r < 4; ++r) {
        const int row = m0 + wm + i * 16 + l4 * 4 + r;
        const float v = acc[i][j][r] + bc;
        if (EPI == 0) {
          outf[(size_t)row * 1024 + col] = v;
        } else {
          const int b = row >> 10, n = row & 1023;
          if (col < 1024) {
            const int h = col >> 6, d = col & 63;
            oq[(((size_t)(b * 16 + h)) * 1024 + n) * 64 + d] =
                (bf16)(v * SCALE2);
          } else {
            const int ckv = col - 1024;
            const int s = ckv >> 10, c2 = ckv & 1023;
            const int h = c2 >> 6, d = c2 & 63;
            if (s == 0)
              ok[(((size_t)(b * 16 + h)) * 1024 + n) * 64 + d] = (bf16)v;
            else
              ovt[(((size_t)(b * 16 + h)) * 64 + d) * 1024 + n] = (bf16)v;
          }
        }
      }
    }
  }
#undef STAGE_B
#undef STAGE_A_ASYNC
#undef LOAD_A_F32
#undef COMMIT_A_F32
}

// ---------------------------------------------------------------------------
// Flash-style masked attention, fixed-max softmax, bit-packed mask, XCD grid
// (bh fastest). Unchanged from round 9.
// ---------------------------------------------------------------------------
__global__ __launch_bounds__(256)
void attn_kernel(const bf16* __restrict__ q, const bf16* __restrict__ k,
                 const bf16* __restrict__ vT, const u64* __restrict__ maskbits,
                 bf16* __restrict__ ao) {
  const int bh = blockIdx.x;
  const int ntile = blockIdx.y;
  const int b = bh >> 4, h = bh & 15;
  const int tid = threadIdx.x;
  const int lane = tid & 63;
  const int w = tid >> 6;
  const int l15 = lane & 15, l4 = lane >> 4;

  __shared__ bf16 Ks[64][72];
  __shared__ bf16 Vts[64][72];
  __shared__ bf16 Pw[4][16][72];

  const size_t base = (size_t)bh * 65536;
  const int nrow0 = ntile * 64 + w * 16;

  bf16x8 qf[2];
#pragma unroll
  for (int ks = 0; ks < 2; ++ks)
    qf[ks] =
        *(const bf16x8*)&q[base + (size_t)(nrow0 + l15) * 64 + ks * 32 + l4 * 8];

  f32x4 o[4] = {};
  float lsum[4] = {0.0f, 0.0f, 0.0f, 0.0f};

  const u64* mb = maskbits + (size_t)(b * 1024 + nrow0) * 16;

  for (int mt = 0; mt < 16; ++mt) {
#pragma unroll
    for (int i = 0; i < 2; ++i) {
      int c = i * 256 + tid;
      int row = c >> 3, col = (c & 7) * 8;
      *(bf16x8*)&Ks[row][col] =
          *(const bf16x8*)&k[base + (size_t)(mt * 64 + row) * 64 + col];
      *(bf16x8*)&Vts[row][col] =
          *(const bf16x8*)&vT[base + (size_t)row * 1024 + mt * 64 + col];
    }
    __syncthreads();

    f32x4 s[4];
#pragma unroll
    for (int sub = 0; sub < 4; ++sub) s[sub] = f32x4{-12.f, -12.f, -12.f, -12.f};
#pragma unroll
    for (int ks = 0; ks < 2; ++ks) {
#pragma unroll
      for (int sub = 0; sub < 4; ++sub) {
        bf16x8 bfr = *(const bf16x8*)&Ks[sub * 16 + l15][ks * 32 + l4 * 8];
        s[sub] = MFMA16(qf[ks], bfr, s[sub]);
      }
    }

    u64 wbits[4];
#pragma unroll
    for (int r = 0; r < 4; ++r) wbits[r] = mb[(size_t)(l4 * 4 + r) * 16 + mt];

#pragma unroll
    for (int sub = 0; sub < 4; ++sub) {
#pragma unroll
      for (int r = 0; r < 4; ++r) {
        float p = exp2f(s[sub][r]);
        p = ((wbits[r] >> (sub * 16 + l15)) & 1) ? p : 0.0f;
        lsum[r] += p;
        Pw[w][l4 * 4 + r][sub * 16 + l15] = (bf16)p;
      }
    }

#pragma unroll
    for (int ks = 0; ks < 2; ++ks) {
      bf16x8 af = *(const bf16x8*)&Pw[w][l15][ks * 32 + l4 * 8];
#pragma unroll
      for (int sub = 0; sub < 4; ++sub) {
        bf16x8 bfr = *(const bf16x8*)&Vts[sub * 16 + l15][ks * 32 + l4 * 8];
        o[sub] = MFMA16(af, bfr, o[sub]);
      }
    }
    __syncthreads();
  }

  float inv[4];
#pragma unroll
  for (int r = 0; r < 4; ++r) {
    float t = lsum[r];
#pragma unroll
    for (int d = 1; d < 16; d <<= 1) t += __shfl_xor(t, d);
    inv[r] = 1.0f / t;
  }

#pragma unroll
  for (int sub = 0; sub < 4; ++sub) {
#pragma unroll
    for (int r = 0; r < 4; ++r) {
      const int n = nrow0 + l4 * 4 + r;
      const size_t idx =
          ((size_t)(b * 1024 + n)) * 1024 + h * 64 + sub * 16 + l15;
      ao[idx] = (bf16)(o[sub][r] * inv[r]);
    }
  }
}

// ---------------------------------------------------------------------------
extern "C" void kernel_launch(void* const* d_in, const int* in_sizes, int n_in,
                              void* d_out, int out_size, void* d_ws,
                              size_t ws_size, hipStream_t stream) {
  const float* x = (const float*)d_in[0];        // [4,1024,1024]
  const float* context = (const float*)d_in[1];  // [4,1024,1024]
  const int* mask = (const int*)d_in[2];         // [4,1024,32,32]
  const float* Wq = (const float*)d_in[3];
  const float* bq = (const float*)d_in[4];
  const float* Wkv = (const float*)d_in[5];
  const float* bkv = (const float*)d_in[6];
  const float* Wp = (const float*)d_in[7];
  const float* bp = (const float*)d_in[8];
  float* out = (float*)d_out;                    // [4,1024,1024] f32

  // Workspace (40.5 MB):
  //  @0    (8 MB): cb (prep->QKV), dead after QKV -> aow reuses it
  //  @8    (6 MB): BqkvT (prep->QKV)
  //  @14   (8 MB): qw   @22 (8 MB): kw   @30 (8 MB): vtw
  //  @38 (0.5 MB): maskbits   @38.5 (2 MB): WpT
  char* ws = (char*)d_ws;
  bf16* cb = (bf16*)(ws);
  bf16* aow = (bf16*)(ws);
  bf16* BqkvT = (bf16*)(ws + (8ull << 20));
  bf16* qw = (bf16*)(ws + (14ull << 20));
  bf16* kw = (bf16*)(ws + (22ull << 20));
  bf16* vtw = (bf16*)(ws + (30ull << 20));
  u64* maskbits = (u64*)(ws + (38ull << 20));
  bf16* WpT = (bf16*)(ws + (38ull << 20) + (512ull << 10));

  const dim3 blk(256);

  // Prep: weight transposes + mask pack + context downcast, one launch.
  prep_k<<<dim3(3328), blk, 0, stream>>>(Wq, Wkv, Wp, mask, context, BqkvT,
                                         WpT, maskbits, cb);

  // Fused QKV projection: dbuf 64x128 tiles, grid (m=64, n=24) -> XCD = m%8.
  // Af1 doubles as both the kv-side f32 pointer slot and (cast) cb source.
  gemm_db<1><<<dim3(64, 24), blk, 0, stream>>>(x, (const float*)cb, nullptr,
                                               BqkvT, bq, bkv, qw, kw, vtw,
                                               nullptr);

  // Attention: grid (bh=64, ntile=16) -> XCD = bh%8.
  attn_kernel<<<dim3(64, 16), blk, 0, stream>>>(qw, kw, vtw, maskbits, aow);

  // Output projection: dbuf, grid (m=64, n=8) -> XCD = m%8.
  gemm_db<0><<<dim3(64, 8), blk, 0, stream>>>(nullptr, nullptr, aow, WpT, bp,
                                              nullptr, nullptr, nullptr,
                                              nullptr, out);
}